// Round 1
// baseline (20787.871 us; speedup 1.0000x reference)
//
#include <hip/hip_runtime.h>
#include <math.h>

#define NG 1000000
#define NV 5143
constexpr int HD = 32;

struct Ptrs { const float* p[35]; };

// LDS layout (floats); all segment starts 16B-aligned where float4-read
enum : int {
  ME_W1=0,     ME_B1=768,   ME_W2=800,   ME_B2=1824,
  PE_W1=1856,  PE_B1=2080,  PE_W2=2112,  PE_B2=3136,
  GE_W1=3168,  GE_B1=5216,  GE_W2=5248,  GE_B2=6272,
  VE_W1=6304,  VE_B1=8352,  VE_W2=8384,  VE_B2=9408,
  MD_W1=9440,  MD_B1=13536, MD_W2=13568, MD_B2=14592, MD_W3=14624, MD_B3=14848,
  LD_W1=14856, LD_B1=18952, LD_W2=18984, LD_B2=20008, LD_W3=20040, LD_B3=22088,
  SW_TOTAL=22152
};

__device__ __forceinline__ float silu_f(float v) {
  return v / (1.0f + __expf(-v));
}

// a[0..31] += xi * w[0..31]   (w in LDS, uniform address -> broadcast)
__device__ __forceinline__ void acc32(float xi, const float* __restrict__ w,
                                      float* __restrict__ a) {
  const float4* w4 = reinterpret_cast<const float4*>(w);
  #pragma unroll
  for (int j = 0; j < 8; ++j) {
    float4 wv = w4[j];
    a[4*j+0] = fmaf(xi, wv.x, a[4*j+0]);
    a[4*j+1] = fmaf(xi, wv.y, a[4*j+1]);
    a[4*j+2] = fmaf(xi, wv.z, a[4*j+2]);
    a[4*j+3] = fmaf(xi, wv.w, a[4*j+3]);
  }
}

// outv = silu(a @ W2 + b2), 32x32
__device__ __forceinline__ void layer2(const float* __restrict__ a,
                                       const float* __restrict__ sw,
                                       int w2off, int b2off,
                                       float* __restrict__ outv) {
  float o[HD];
  #pragma unroll
  for (int j = 0; j < HD; ++j) o[j] = sw[b2off + j];
  #pragma unroll
  for (int i = 0; i < HD; ++i) acc32(a[i], sw + w2off + i*HD, o);
  #pragma unroll
  for (int j = 0; j < HD; ++j) outv[j] = silu_f(o[j]);
}

// fold one encoder's 32 outputs into md/ld layer-1 accumulators
__device__ __forceinline__ void fold128(const float* __restrict__ enc,
                                        const float* __restrict__ sw, int base,
                                        float* __restrict__ amd,
                                        float* __restrict__ ald) {
  #pragma unroll
  for (int i = 0; i < HD; ++i) {
    acc32(enc[i], sw + MD_W1 + (base + i)*HD, amd);
    acc32(enc[i], sw + LD_W1 + (base + i)*HD, ald);
  }
}

__global__ __launch_bounds__(512)
void flame_fwd(Ptrs P, float* __restrict__ out) {
  __shared__ float sw[SW_TOTAL];
  {
    constexpr int SIDX[28] = {7,8,9,10,11,12,13,14,15,16,17,18,19,20,21,22,
                              23,24,25,26,27,28,29,30,31,32,33,34};
    constexpr int SOFF[28] = {ME_W1,ME_B1,ME_W2,ME_B2, PE_W1,PE_B1,PE_W2,PE_B2,
                              GE_W1,GE_B1,GE_W2,GE_B2, VE_W1,VE_B1,VE_W2,VE_B2,
                              MD_W1,MD_B1,MD_W2,MD_B2,MD_W3,MD_B3,
                              LD_W1,LD_B1,LD_W2,LD_B2,LD_W3,LD_B3};
    constexpr int SCNT[28] = {768,32,1024,32, 224,32,1024,32,
                              2048,32,1024,32, 2048,32,1024,32,
                              4096,32,1024,32,224,7,
                              4096,32,1024,32,2048,64};
    #pragma unroll
    for (int s = 0; s < 28; ++s) {
      const float* src = P.p[SIDX[s]];
      for (int i = threadIdx.x; i < SCNT[s]; i += 512)
        sw[SOFF[s] + i] = src[i];
    }
  }
  __syncthreads();

  int t = blockIdx.x * 512 + threadIdx.x;
  if (t >= NG) return;

  const float* means = P.p[0];
  const float* quats = P.p[1];
  const float* feats = P.p[2];
  const float* vmot  = P.p[3];
  const float* cano  = P.p[4];
  const int*   nidx  = (const int*)P.p[5];
  const float* emb   = P.p[6];

  float m0 = means[3*t+0], m1 = means[3*t+1], m2 = means[3*t+2];
  float q0 = quats[4*t+0], q1 = quats[4*t+1], q2 = quats[4*t+2], q3 = quats[4*t+3];
  int v0 = nidx[3*t+0], v1 = nidx[3*t+1], v2 = nidx[3*t+2];

  // inverse-distance weights over 3 neighbors
  float w0, w1, w2;
  {
    float dx = m0 - cano[3*v0+0], dy = m1 - cano[3*v0+1], dz = m2 - cano[3*v0+2];
    w0 = 1.0f / (sqrtf(dx*dx + dy*dy + dz*dz) + 1e-8f);
    dx = m0 - cano[3*v1+0]; dy = m1 - cano[3*v1+1]; dz = m2 - cano[3*v1+2];
    w1 = 1.0f / (sqrtf(dx*dx + dy*dy + dz*dz) + 1e-8f);
    dx = m0 - cano[3*v2+0]; dy = m1 - cano[3*v2+1]; dz = m2 - cano[3*v2+2];
    w2 = 1.0f / (sqrtf(dx*dx + dy*dy + dz*dz) + 1e-8f);
    float s = 1.0f / (w0 + w1 + w2);
    w0 *= s; w1 *= s; w2 *= s;
  }

  // md/ld layer-1 accumulators (x[128] never materialized: fold per-encoder)
  float amd[HD], ald[HD];
  #pragma unroll
  for (int j = 0; j < HD; ++j) { amd[j] = sw[MD_B1 + j]; ald[j] = sw[LD_B1 + j]; }

  float enc[HD];

  // ===== motion encoder (input: nmv[24] = weighted vm gather) =====
  {
    float a[HD];
    #pragma unroll
    for (int j = 0; j < HD; ++j) a[j] = sw[ME_B1 + j];
    #pragma unroll
    for (int w = 0; w < 8; ++w) {
      const float* p0 = vmot + (w*NV + v0)*3;
      const float* p1 = vmot + (w*NV + v1)*3;
      const float* p2 = vmot + (w*NV + v2)*3;
      #pragma unroll
      for (int c = 0; c < 3; ++c) {
        float xi = w0*p0[c] + w1*p1[c] + w2*p2[c];
        acc32(xi, sw + ME_W1 + (w*3 + c)*HD, a);
      }
    }
    #pragma unroll
    for (int j = 0; j < HD; ++j) a[j] = silu_f(a[j]);
    layer2(a, sw, ME_W2, ME_B2, enc);
  }
  fold128(enc, sw, 0, amd, ald);

  // ===== position encoder (input: [means, quats] = 7) =====
  {
    float a[HD];
    #pragma unroll
    for (int j = 0; j < HD; ++j) a[j] = sw[PE_B1 + j];
    acc32(m0, sw + PE_W1 + 0*HD, a);
    acc32(m1, sw + PE_W1 + 1*HD, a);
    acc32(m2, sw + PE_W1 + 2*HD, a);
    acc32(q0, sw + PE_W1 + 3*HD, a);
    acc32(q1, sw + PE_W1 + 4*HD, a);
    acc32(q2, sw + PE_W1 + 5*HD, a);
    acc32(q3, sw + PE_W1 + 6*HD, a);
    #pragma unroll
    for (int j = 0; j < HD; ++j) a[j] = silu_f(a[j]);
    layer2(a, sw, PE_W2, PE_B2, enc);
  }
  fold128(enc, sw, 32, amd, ald);

  // ===== gaussian (feature) encoder — stream features from global =====
  {
    float a[HD];
    #pragma unroll
    for (int j = 0; j < HD; ++j) a[j] = sw[GE_B1 + j];
    const float* frow = feats + (long)t * 64;
    #pragma unroll 2
    for (int i = 0; i < 64; i += 4) {
      float4 f = *reinterpret_cast<const float4*>(frow + i);
      acc32(f.x, sw + GE_W1 + (i+0)*HD, a);
      acc32(f.y, sw + GE_W1 + (i+1)*HD, a);
      acc32(f.z, sw + GE_W1 + (i+2)*HD, a);
      acc32(f.w, sw + GE_W1 + (i+3)*HD, a);
    }
    #pragma unroll
    for (int j = 0; j < HD; ++j) a[j] = silu_f(a[j]);
    layer2(a, sw, GE_W2, GE_B2, enc);
  }
  fold128(enc, sw, 64, amd, ald);

  // ===== flame-vertex encoder — stream nlat = weighted emb gather =====
  {
    float a[HD];
    #pragma unroll
    for (int j = 0; j < HD; ++j) a[j] = sw[VE_B1 + j];
    const float* e0 = emb + (long)v0 * 64;
    const float* e1 = emb + (long)v1 * 64;
    const float* e2 = emb + (long)v2 * 64;
    #pragma unroll 2
    for (int i = 0; i < 64; i += 4) {
      float4 f0 = *reinterpret_cast<const float4*>(e0 + i);
      float4 f1 = *reinterpret_cast<const float4*>(e1 + i);
      float4 f2 = *reinterpret_cast<const float4*>(e2 + i);
      acc32(w0*f0.x + w1*f1.x + w2*f2.x, sw + VE_W1 + (i+0)*HD, a);
      acc32(w0*f0.y + w1*f1.y + w2*f2.y, sw + VE_W1 + (i+1)*HD, a);
      acc32(w0*f0.z + w1*f1.z + w2*f2.z, sw + VE_W1 + (i+2)*HD, a);
      acc32(w0*f0.w + w1*f1.w + w2*f2.w, sw + VE_W1 + (i+3)*HD, a);
    }
    #pragma unroll
    for (int j = 0; j < HD; ++j) a[j] = silu_f(a[j]);
    layer2(a, sw, VE_W2, VE_B2, enc);
  }
  fold128(enc, sw, 96, amd, ald);

  // ===== motion decoder: silu(amd) -> 32x32+silu -> 32x7 linear =====
  {
    #pragma unroll
    for (int j = 0; j < HD; ++j) amd[j] = silu_f(amd[j]);
    float h[HD];
    layer2(amd, sw, MD_W2, MD_B2, h);
    float mv[7];
    #pragma unroll
    for (int jo = 0; jo < 7; ++jo) {
      float s = sw[MD_B3 + jo];
      #pragma unroll
      for (int i = 0; i < HD; ++i) s = fmaf(h[i], sw[MD_W3 + i*7 + jo], s);
      mv[jo] = s;
    }
    out[3*t+0] = m0 + 0.001f*mv[0];
    out[3*t+1] = m1 + 0.001f*mv[1];
    out[3*t+2] = m2 + 0.001f*mv[2];
    float* oq = out + 3*NG;
    oq[4*t+0] = q0 + 0.01f*mv[3];
    oq[4*t+1] = q1 + 0.01f*mv[4];
    oq[4*t+2] = q2 + 0.01f*mv[5];
    oq[4*t+3] = q3 + 0.01f*mv[6];
  }

  // ===== latent decoder: silu(ald) -> 32x32+silu -> 32x64 linear =====
  {
    #pragma unroll
    for (int j = 0; j < HD; ++j) ald[j] = silu_f(ald[j]);
    float h[HD];
    layer2(ald, sw, LD_W2, LD_B2, h);
    float o0[HD], o1[HD];
    #pragma unroll
    for (int j = 0; j < HD; ++j) { o0[j] = sw[LD_B3 + j]; o1[j] = sw[LD_B3 + 32 + j]; }
    #pragma unroll
    for (int i = 0; i < HD; ++i) {
      acc32(h[i], sw + LD_W3 + i*64,      o0);
      acc32(h[i], sw + LD_W3 + i*64 + 32, o1);
    }
    float* of = out + (long)7*NG + (long)t*64;
    float4* of4 = reinterpret_cast<float4*>(of);
    #pragma unroll
    for (int j = 0; j < 8; ++j) {
      of4[j]   = make_float4(o0[4*j], o0[4*j+1], o0[4*j+2], o0[4*j+3]);
      of4[j+8] = make_float4(o1[4*j], o1[4*j+1], o1[4*j+2], o1[4*j+3]);
    }
  }

  if (t == 0) out[(long)71*NG] = 1.0f;  // cache_hit_rate
}

extern "C" void kernel_launch(void* const* d_in, const int* in_sizes, int n_in,
                              void* d_out, int out_size, void* d_ws, size_t ws_size,
                              hipStream_t stream) {
  (void)in_sizes; (void)n_in; (void)d_ws; (void)ws_size; (void)out_size;
  Ptrs P;
  for (int i = 0; i < 35; ++i) P.p[i] = (const float*)d_in[i];
  float* out = (float*)d_out;
  int blocks = (NG + 511) / 512;
  flame_fwd<<<blocks, 512, 0, stream>>>(P, out);
}